// Round 12
// baseline (2150.806 us; speedup 1.0000x reference)
//
#include <hip/hip_runtime.h>

#define NB   8
#define NP   8192
#define NS   2048
#define NK   16
#define DIN  64
#define DOUT 128
#define BN_EPS 1e-5f

#define MT   1024           // mega-kernel block size (4 waves/SIMD latency overlap)
#define NW   248            // worker blocks (grid = 8 fps + 248 workers = 256 CUs)
#define FP   (NP / MT)      // 8 fps points per thread
#define FW   (MT / 64)      // 16 waves
#define KJ   (NP / MT)      // 8 knn points per thread
#define KBINS 64
#define MAXC 512

// ---------------- f64-packed argmax helpers --------------------------------------
// packed u64 = (fp32 dist bits << 32) | ~idx, as double (sign bit 0 -> numeric
// order == u64 order): fmax == (max dist, tie -> min idx).
__device__ __forceinline__ double pack_di(float d, unsigned lo)
{
    unsigned long long u = ((unsigned long long)__float_as_uint(d) << 32) | lo;
    return __longlong_as_double((long long)u);
}

template<int CTRL, int RMASK>
__device__ __forceinline__ double dpp_max_f64(double v)
{
    unsigned long long u = (unsigned long long)__double_as_longlong(v);
    unsigned hi = (unsigned)(u >> 32), lo = (unsigned)u;
    unsigned th = (unsigned)__builtin_amdgcn_update_dpp((int)hi, (int)hi, CTRL, RMASK, 0xF, false);
    unsigned tl = (unsigned)__builtin_amdgcn_update_dpp((int)lo, (int)lo, CTRL, RMASK, 0xF, false);
    double o = __longlong_as_double((long long)(((unsigned long long)th << 32) | tl));
    return fmax(v, o);
}

__device__ __forceinline__ int knn_bin(float d)
{
    int e = (int)(__float_as_uint(d) >> 23) - 90;   // monotone, clamped octave bins
    return e < 0 ? 0 : (e > 63 ? 63 : e);
}

// ---------------- mega kernel: 8 fps producers + 248 persistent workers --------
struct FpsS {
    float4 sxyz[NP];                    // 128 KB
    int sel[NS];                        // 8 KB
    unsigned long long rv64[2][FW];     // 256 B
};
struct KnnS {
    float sdist[NP];                    // 32 KB
    unsigned hist[32][KBINS];           // 8 KB
    float cd[MAXC];
    int   ci[MAXC];
    int   sidx[NK];
    float sf[NK][DIN];                  // 4 KB gathered feat rows
    float red[8][DOUT];                 // 4 KB cross-group max
    float wt[DIN * DOUT];               // 32 KB folded weights (LDS-resident)
    float cbv[DOUT];                    // 512 B folded bias
    unsigned ccnt;
    int cut;
};
union MegaS { FpsS f; KnnS k; };
// union = ~136.5 KB -> 1 block/CU; grid 256 -> all blocks co-resident,
// so producer progress never depends on dispatch order (deadlock-safe).

__global__ __launch_bounds__(MT, 1)
void mega_kernel(const float* __restrict__ coords, float* __restrict__ out_coords,
                 const float* __restrict__ feat, const float* __restrict__ W,
                 const float* __restrict__ bias, const float* __restrict__ gamma,
                 const float* __restrict__ beta, const float* __restrict__ rmean,
                 const float* __restrict__ rvar, float* __restrict__ outF,
                 unsigned* __restrict__ flags)
{
#pragma clang fp contract(off)
    __shared__ MegaS smem;
    const int t = threadIdx.x;

    if (blockIdx.x < NB) {
        // ================= FPS producer (1 block per batch) =================
        // plain-scalar arrays (pairing them regressed twice: R9 asm, R10 v2f)
        const int b = blockIdx.x;
        const float* cb = coords + (size_t)b * NP * 3;

        for (int i = t; i < NP; i += MT)
            smem.f.sxyz[i] = make_float4(cb[i * 3 + 0], cb[i * 3 + 1], cb[i * 3 + 2], 0.0f);
        __syncthreads();

        float px[FP], py[FP], pz[FP], dist[FP];
#pragma unroll
        for (int k = 0; k < FP; ++k) {
            float4 p = smem.f.sxyz[t + k * MT];
            px[k] = p.x; py[k] = p.y; pz[k] = p.z;
            dist[k] = 1e10f;
        }

        const int wave = t >> 6, lane = t & 63;
        const unsigned nt = ~(unsigned)t;          // ~(t + k*MT) == nt - k*MT
        int cur = 0;

        for (int s = 0; s < NS; ++s) {
            if (t == 0) smem.f.sel[s] = cur;
            const float4 cc = smem.f.sxyz[cur];
            const float cx = cc.x, cy = cc.y, cz = cc.z;

            // min-dist update + f32 dual-chain max (full-rate scalar)
            float m0 = -1.0f, m1 = -1.0f;
#pragma unroll
            for (int k = 0; k < FP; ++k) {
                float dx = px[k] - cx, dy = py[k] - cy, dz = pz[k] - cz;
                float d = fmaf(dz, dz, fmaf(dy, dy, dx * dx));
                float nd = fminf(dist[k], d);
                dist[k] = nd;
                if (k & 1) m1 = fmaxf(m1, nd);
                else       m0 = fmaxf(m0, nd);
            }
            float m = fmaxf(m0, m1);
            // recover smallest k attaining m: independent compares -> or-tree -> ctz
            unsigned msk = 0;
#pragma unroll
            for (int k = 0; k < FP; ++k)
                msk |= (dist[k] == m) ? (1u << k) : 0u;
            int kk = __builtin_ctz(msk);
            double best = pack_di(m, nt - (unsigned)(kk * MT));

            // wave argmax: 6 DPP f64-max levels -> lane 63 holds wave max
            best = dpp_max_f64<0xB1,  0xF>(best);  // quad_perm xor1
            best = dpp_max_f64<0x4E,  0xF>(best);  // quad_perm xor2
            best = dpp_max_f64<0x124, 0xF>(best);  // row_ror:4
            best = dpp_max_f64<0x128, 0xF>(best);  // row_ror:8
            best = dpp_max_f64<0x142, 0xA>(best);  // row_bcast15
            best = dpp_max_f64<0x143, 0xC>(best);  // row_bcast31

            int pb = s & 1;
            if (lane == 63) smem.f.rv64[pb][wave] = (unsigned long long)__double_as_longlong(best);
            __syncthreads();

            // cross-wave: b64 read of partial[lane&15]; row of 16 distinct
            // values fully reduces in 4 DPP levels (xor1, xor2, ror4, ror8)
            double g = __longlong_as_double((long long)smem.f.rv64[pb][lane & 15]);
            g = dpp_max_f64<0xB1,  0xF>(g);
            g = dpp_max_f64<0x4E,  0xF>(g);
            g = dpp_max_f64<0x124, 0xF>(g);
            g = dpp_max_f64<0x128, 0xF>(g);
            cur = (int)~(unsigned)(unsigned long long)__double_as_longlong(g);

            // publish a 32-query granule (wave 0 only: program-order release
            // covers the wave's own coord stores)
            if ((s & 31) == 31) {
                int base = s - 31;
                if (t < 32) {
                    float4 p = smem.f.sxyz[smem.f.sel[base + t]];
                    float* dst = out_coords + ((size_t)b * NS + base + t) * 3;
                    dst[0] = p.x; dst[1] = p.y; dst[2] = p.z;
                }
                if (t == 0)
                    __hip_atomic_store(&flags[b * 16], (unsigned)((s + 1) >> 5),
                                       __ATOMIC_RELEASE, __HIP_MEMORY_SCOPE_AGENT);
            }
        }
    } else {
        // ===== persistent worker: knn + fused gather/MLP/max per query =====
        const int wid = blockIdx.x - NB;           // 0..247
        const int c = t & 31;
        const int o = t & (DOUT - 1);
        const int grp = t >> 7;                    // 0..7

        // fold BN into weights, LDS-resident (once per worker block)
        for (int i = t; i < DIN * DOUT; i += MT) {
            int oo = i & (DOUT - 1), kk = i >> 7;
            smem.k.wt[i] = W[oo * DIN + kk] * (gamma[oo] * rsqrtf(rvar[oo] + BN_EPS));
        }
        if (t < DOUT)
            smem.k.cbv[t] = (bias[t] - rmean[t]) * (gamma[t] * rsqrtf(rvar[t] + BN_EPS)) + beta[t];
        __syncthreads();

        for (int j = wid; j < NB * NS; j += NW) {
            const int s = j >> 3, b = j & 7;       // ascending s per worker
            const int q = b * NS + s;

            if (t == 0) {
                const unsigned need = (unsigned)(s >> 5) + 1;
                while (__hip_atomic_load(&flags[b * 16], __ATOMIC_ACQUIRE,
                                         __HIP_MEMORY_SCOPE_AGENT) < need)
                    __builtin_amdgcn_s_sleep(32);
            }
            __syncthreads();

            const float* cb = coords + (size_t)b * NP * 3;
            const float* qp = out_coords + (size_t)q * 3;
            const float qx = qp[0], qy = qp[1], qz = qp[2];

            for (int i = t; i < 32 * KBINS; i += MT) ((unsigned*)smem.k.hist)[i] = 0;
            if (t == 0) smem.k.ccnt = 0;
            __syncthreads();

            for (int jj = 0; jj < KJ; ++jj) {
                int i = t + jj * MT;
                float dx = cb[i * 3 + 0] - qx, dy = cb[i * 3 + 1] - qy, dz = cb[i * 3 + 2] - qz;
                float d = fmaf(dz, dz, fmaf(dy, dy, dx * dx));
                smem.k.sdist[i] = d;
                atomicAdd(&smem.k.hist[c][knn_bin(d)], 1u);
            }
            __syncthreads();

            if (t < 64) {
                unsigned total = 0;
#pragma unroll
                for (int cc = 0; cc < 32; ++cc) total += smem.k.hist[cc][t];
                unsigned incl = total;
#pragma unroll
                for (int off = 1; off < 64; off <<= 1) {
                    unsigned n = __shfl_up(incl, off);
                    if (t >= off) incl += n;
                }
                unsigned excl = incl - total;
                if (excl < NK && incl >= NK) smem.k.cut = t;
            }
            __syncthreads();

            const int cut = smem.k.cut;
            for (int jj = 0; jj < KJ; ++jj) {
                int i = t + jj * MT;
                float d = smem.k.sdist[i];
                if (knn_bin(d) <= cut) {
                    unsigned p = atomicAdd(&smem.k.ccnt, 1u);
                    if (p < MAXC) { smem.k.cd[p] = d; smem.k.ci[p] = i; }
                }
            }
            __syncthreads();

            // parallel rank-select: rank = #{(dj,ij) < (d,i)}; unique ranks -> LDS
            int cnt = (int)(smem.k.ccnt < (unsigned)MAXC ? smem.k.ccnt : (unsigned)MAXC);
            for (int p = t; p < cnt; p += MT) {
                float d = smem.k.cd[p]; int idx = smem.k.ci[p];
                int rank = 0;
                for (int jj = 0; jj < cnt; ++jj) {
                    float dj = smem.k.cd[jj]; int ij = smem.k.ci[jj];
                    rank += (dj < d || (dj == d && ij < idx)) ? 1 : 0;
                }
                if (rank < NK) smem.k.sidx[rank] = idx;
            }
            __syncthreads();

            // gather 16 neighbor feat rows in one pass (1024 = 16 rows x 64 cols)
            {
                int row = t >> 6;                  // 0..15
                smem.k.sf[row][t & 63] =
                    feat[((size_t)b * NP + smem.k.sidx[row]) * DIN + (t & 63)];
            }
            __syncthreads();

            // fused MLP+relu+max: thread handles out-channel o, neighbors
            // {grp, grp+8}; cross-group max via LDS
            const float cb0 = smem.k.cbv[o];
            float mx = -3.4e38f;
#pragma unroll
            for (int nn = 0; nn < 2; ++nn) {
                const float4* f4 = (const float4*)smem.k.sf[grp + nn * 8];
                float acc = cb0;
#pragma unroll
                for (int k4 = 0; k4 < DIN / 4; ++k4) {
                    float4 f = f4[k4];
                    acc = fmaf(f.x, smem.k.wt[(k4 * 4 + 0) * DOUT + o], acc);
                    acc = fmaf(f.y, smem.k.wt[(k4 * 4 + 1) * DOUT + o], acc);
                    acc = fmaf(f.z, smem.k.wt[(k4 * 4 + 2) * DOUT + o], acc);
                    acc = fmaf(f.w, smem.k.wt[(k4 * 4 + 3) * DOUT + o], acc);
                }
                mx = fmaxf(mx, fmaxf(acc, 0.0f));
            }
            smem.k.red[grp][o] = mx;
            __syncthreads();

            if (t < DOUT) {
                float v0 = fmaxf(fmaxf(smem.k.red[0][t], smem.k.red[1][t]),
                                 fmaxf(smem.k.red[2][t], smem.k.red[3][t]));
                float v1 = fmaxf(fmaxf(smem.k.red[4][t], smem.k.red[5][t]),
                                 fmaxf(smem.k.red[6][t], smem.k.red[7][t]));
                outF[(size_t)q * DOUT + t] = fmaxf(v0, v1);
            }
            __syncthreads();
        }
    }
}

extern "C" void kernel_launch(void* const* d_in, const int* in_sizes, int n_in,
                              void* d_out, int out_size, void* d_ws, size_t ws_size,
                              hipStream_t stream)
{
    const float* coords = (const float*)d_in[0];
    const float* feat   = (const float*)d_in[1];
    const float* W      = (const float*)d_in[2];
    const float* bias   = (const float*)d_in[3];
    const float* gamma  = (const float*)d_in[4];
    const float* beta   = (const float*)d_in[5];
    const float* rmean  = (const float*)d_in[6];
    const float* rvar   = (const float*)d_in[7];

    float* out_coords = (float*)d_out;                    // [8,2048,3]
    float* out_feat   = out_coords + (size_t)NB * NS * 3; // [8,2048,128]

    unsigned* flags = (unsigned*)d_ws;                    // 8 flags, 64B apart

    hipMemsetAsync(flags, 0, 8 * 16 * sizeof(unsigned), stream);
    mega_kernel<<<NB + NW, MT, 0, stream>>>(
        coords, out_coords, feat, W, bias, gamma, beta, rmean, rvar,
        out_feat, flags);
}

// Round 13
// 1649.434 us; speedup vs baseline: 1.3040x; 1.3040x over previous
//
#include <hip/hip_runtime.h>

#define NB   8
#define NP   8192
#define NS   2048
#define NK   16
#define DIN  64
#define DOUT 128
#define BN_EPS 1e-5f

#define MT   512            // mega-kernel block size
#define NW   248            // worker blocks (grid = 8 fps + 248 workers = 256 CUs)
#define FP   (NP / MT)      // 16 fps points per thread
#define FW   (MT / 64)      // 8 waves
#define KJ   (NP / MT)      // 16 knn points per thread
#define KBINS 64
#define MAXC 512

// ---------------- K0: fold BN into weights, transpose to [k][o] ----------------
__global__ void fold_weights_kernel(const float* __restrict__ W, const float* __restrict__ bias,
                                    const float* __restrict__ gamma, const float* __restrict__ beta,
                                    const float* __restrict__ rmean, const float* __restrict__ rvar,
                                    float* __restrict__ Wt, float* __restrict__ Cb)
{
    int i = blockIdx.x * 256 + threadIdx.x;
    if (i < DIN * DOUT) {
        int o = i & (DOUT - 1);
        int k = i >> 7;
        float sc = gamma[o] * rsqrtf(rvar[o] + BN_EPS);
        Wt[i] = W[o * DIN + k] * sc;            // Wt[k*128 + o]
        if (i < DOUT) {
            Cb[i] = (bias[i] - rmean[i]) * sc + beta[i];
        }
    }
}

// ---------------- f64-packed argmax helpers --------------------------------------
// packed u64 = (fp32 dist bits << 32) | ~idx, as double (sign bit 0 -> numeric
// order == u64 order): fmax == (max dist, tie -> min idx).
__device__ __forceinline__ double pack_di(float d, unsigned lo)
{
    unsigned long long u = ((unsigned long long)__float_as_uint(d) << 32) | lo;
    return __longlong_as_double((long long)u);
}

template<int CTRL, int RMASK>
__device__ __forceinline__ double dpp_max_f64(double v)
{
    unsigned long long u = (unsigned long long)__double_as_longlong(v);
    unsigned hi = (unsigned)(u >> 32), lo = (unsigned)u;
    unsigned th = (unsigned)__builtin_amdgcn_update_dpp((int)hi, (int)hi, CTRL, RMASK, 0xF, false);
    unsigned tl = (unsigned)__builtin_amdgcn_update_dpp((int)lo, (int)lo, CTRL, RMASK, 0xF, false);
    double o = __longlong_as_double((long long)(((unsigned long long)th << 32) | tl));
    return fmax(v, o);
}

__device__ __forceinline__ int knn_bin(float d)
{
    int e = (int)(__float_as_uint(d) >> 23) - 90;   // monotone, clamped octave bins
    return e < 0 ? 0 : (e > 63 ? 63 : e);
}

// ---------------- mega kernel: 8 fps producers + 248 persistent workers --------
struct FpsS {
    float4 sxyz[NP];                    // 128 KB
    int sel[NS];                        // 8 KB
    unsigned long long rv64[2][FW];
};
struct KnnS {
    float sdist[NP];                    // 32 KB
    unsigned hist[32][KBINS];           // 8 KB
    float cd[MAXC];
    int   ci[MAXC];
    int   sidx[NK];
    float sf[NK][DIN];                  // 4 KB gathered feat rows
    float red[4][DOUT];                 // 2 KB cross-group max
    unsigned ccnt;
    int cut;
};
union MegaS { FpsS f; KnnS k; };
// union = ~139 KB -> 1 block/CU; grid 256 -> all blocks co-resident,
// so producer progress never depends on dispatch order (deadlock-safe).

__global__ __launch_bounds__(MT, 1)
void mega_kernel(const float* __restrict__ coords, float* __restrict__ out_coords,
                 const float* __restrict__ feat, const float* __restrict__ Wt,
                 const float* __restrict__ Cb, float* __restrict__ outF,
                 unsigned* __restrict__ flags)
{
#pragma clang fp contract(off)
    __shared__ MegaS smem;
    const int t = threadIdx.x;

    if (blockIdx.x < NB) {
        // ================= FPS producer (1 block per batch) =================
        // 512t / 2 waves/SIMD is the measured optimum (256t: +1500us, 1024t:
        // +475us, any reg-pairing of the arrays: +225us). Keep scalar.
        const int b = blockIdx.x;
        const float* cb = coords + (size_t)b * NP * 3;

        for (int i = t; i < NP; i += MT)
            smem.f.sxyz[i] = make_float4(cb[i * 3 + 0], cb[i * 3 + 1], cb[i * 3 + 2], 0.0f);
        __syncthreads();

        float px[FP], py[FP], pz[FP], dist[FP];
#pragma unroll
        for (int k = 0; k < FP; ++k) {
            float4 p = smem.f.sxyz[t + k * MT];
            px[k] = p.x; py[k] = p.y; pz[k] = p.z;
            dist[k] = 1e10f;
        }

        const int wave = t >> 6, lane = t & 63;
        const unsigned nt = ~(unsigned)t;          // ~(t + k*MT) == nt - k*MT
        int cur = 0;

        for (int s = 0; s < NS; ++s) {
            if (t == 0) smem.f.sel[s] = cur;
            const float4 cc = smem.f.sxyz[cur];
            const float cx = cc.x, cy = cc.y, cz = cc.z;

            // min-dist update + f32 dual-chain max (full-rate scalar)
            float m0 = -1.0f, m1 = -1.0f;
#pragma unroll
            for (int k = 0; k < FP; ++k) {
                float dx = px[k] - cx, dy = py[k] - cy, dz = pz[k] - cz;
                float d = fmaf(dz, dz, fmaf(dy, dy, dx * dx));
                float nd = fminf(dist[k], d);
                dist[k] = nd;
                if (k & 1) m1 = fmaxf(m1, nd);
                else       m0 = fmaxf(m0, nd);
            }
            float m = fmaxf(m0, m1);
            // recover smallest k attaining m (descending cndmask chain)
            int kk = 0;
#pragma unroll
            for (int k = FP - 1; k >= 0; --k)
                if (dist[k] == m) kk = k;
            double best = pack_di(m, nt - (unsigned)(kk * MT));

            // wave argmax: 6 DPP f64-max levels -> lane 63 holds wave max
            best = dpp_max_f64<0xB1,  0xF>(best);  // quad_perm xor1
            best = dpp_max_f64<0x4E,  0xF>(best);  // quad_perm xor2
            best = dpp_max_f64<0x124, 0xF>(best);  // row_ror:4
            best = dpp_max_f64<0x128, 0xF>(best);  // row_ror:8
            best = dpp_max_f64<0x142, 0xA>(best);  // row_bcast15
            best = dpp_max_f64<0x143, 0xC>(best);  // row_bcast31

            int pb = s & 1;
            if (lane == 63) smem.f.rv64[pb][wave] = (unsigned long long)__double_as_longlong(best);
            __syncthreads();

            // cross-wave: b64 read of partial[lane&7], 4 DPP levels over row-of-16
            double g = __longlong_as_double((long long)smem.f.rv64[pb][lane & 7]);
            g = dpp_max_f64<0xB1,  0xF>(g);
            g = dpp_max_f64<0x4E,  0xF>(g);
            g = dpp_max_f64<0x124, 0xF>(g);
            g = dpp_max_f64<0x128, 0xF>(g);
            cur = (int)~(unsigned)(unsigned long long)__double_as_longlong(g);

            // publish a 32-query granule (wave 0 only: program-order release
            // covers the wave's own coord stores)
            if ((s & 31) == 31) {
                int base = s - 31;
                if (t < 32) {
                    float4 p = smem.f.sxyz[smem.f.sel[base + t]];
                    float* dst = out_coords + ((size_t)b * NS + base + t) * 3;
                    dst[0] = p.x; dst[1] = p.y; dst[2] = p.z;
                }
                if (t == 0)
                    __hip_atomic_store(&flags[b * 16], (unsigned)((s + 1) >> 5),
                                       __ATOMIC_RELEASE, __HIP_MEMORY_SCOPE_AGENT);
            }
        }
    } else {
        // ===== persistent worker: knn + fused gather/MLP/max per query =====
        const int wid = blockIdx.x - NB;           // 0..247
        const int c = t & 31;
        const int o = t & (DOUT - 1);
        const int grp = t >> 7;                    // 0..3

        for (int j = wid; j < NB * NS; j += NW) {
            const int s = j >> 3, b = j & 7;       // ascending s per worker
            const int q = b * NS + s;

            if (t == 0) {
                const unsigned need = (unsigned)(s >> 5) + 1;
                while (__hip_atomic_load(&flags[b * 16], __ATOMIC_ACQUIRE,
                                         __HIP_MEMORY_SCOPE_AGENT) < need)
                    __builtin_amdgcn_s_sleep(32);
            }
            __syncthreads();

            const float* cb = coords + (size_t)b * NP * 3;
            const float* qp = out_coords + (size_t)q * 3;
            const float qx = qp[0], qy = qp[1], qz = qp[2];

            for (int i = t; i < 32 * KBINS; i += MT) ((unsigned*)smem.k.hist)[i] = 0;
            if (t == 0) smem.k.ccnt = 0;
            __syncthreads();

            for (int jj = 0; jj < KJ; ++jj) {
                int i = t + jj * MT;
                float dx = cb[i * 3 + 0] - qx, dy = cb[i * 3 + 1] - qy, dz = cb[i * 3 + 2] - qz;
                float d = fmaf(dz, dz, fmaf(dy, dy, dx * dx));
                smem.k.sdist[i] = d;
                atomicAdd(&smem.k.hist[c][knn_bin(d)], 1u);
            }
            __syncthreads();

            if (t < 64) {
                unsigned total = 0;
#pragma unroll
                for (int cc = 0; cc < 32; ++cc) total += smem.k.hist[cc][t];
                unsigned incl = total;
#pragma unroll
                for (int off = 1; off < 64; off <<= 1) {
                    unsigned n = __shfl_up(incl, off);
                    if (t >= off) incl += n;
                }
                unsigned excl = incl - total;
                if (excl < NK && incl >= NK) smem.k.cut = t;
            }
            __syncthreads();

            const int cut = smem.k.cut;
            for (int jj = 0; jj < KJ; ++jj) {
                int i = t + jj * MT;
                float d = smem.k.sdist[i];
                if (knn_bin(d) <= cut) {
                    unsigned p = atomicAdd(&smem.k.ccnt, 1u);
                    if (p < MAXC) { smem.k.cd[p] = d; smem.k.ci[p] = i; }
                }
            }
            __syncthreads();

            // parallel rank-select: rank = #{(dj,ij) < (d,i)}; unique ranks -> LDS
            int cnt = (int)(smem.k.ccnt < (unsigned)MAXC ? smem.k.ccnt : (unsigned)MAXC);
            for (int p = t; p < cnt; p += MT) {
                float d = smem.k.cd[p]; int idx = smem.k.ci[p];
                int rank = 0;
                for (int jj = 0; jj < cnt; ++jj) {
                    float dj = smem.k.cd[jj]; int ij = smem.k.ci[jj];
                    rank += (dj < d || (dj == d && ij < idx)) ? 1 : 0;
                }
                if (rank < NK) smem.k.sidx[rank] = idx;
            }
            __syncthreads();

            // gather 16 neighbor feat rows (coalesced 256-B rows)
#pragma unroll
            for (int rr = 0; rr < 2; ++rr) {
                int row = (t >> 6) + rr * 8;       // 0..15
                smem.k.sf[row][t & 63] =
                    feat[((size_t)b * NP + smem.k.sidx[row]) * DIN + (t & 63)];
            }
            __syncthreads();

            // fused MLP+relu+max: thread handles out-channel o, neighbors
            // {grp, grp+4, grp+8, grp+12}; cross-group max via LDS
            const float cb0 = Cb[o];
            float mx = -3.4e38f;
#pragma unroll
            for (int nn = 0; nn < 4; ++nn) {
                const float4* f4 = (const float4*)smem.k.sf[grp + nn * 4];
                float acc = cb0;
#pragma unroll
                for (int k4 = 0; k4 < DIN / 4; ++k4) {
                    float4 f = f4[k4];
                    acc = fmaf(f.x, Wt[(k4 * 4 + 0) * DOUT + o], acc);
                    acc = fmaf(f.y, Wt[(k4 * 4 + 1) * DOUT + o], acc);
                    acc = fmaf(f.z, Wt[(k4 * 4 + 2) * DOUT + o], acc);
                    acc = fmaf(f.w, Wt[(k4 * 4 + 3) * DOUT + o], acc);
                }
                mx = fmaxf(mx, fmaxf(acc, 0.0f));
            }
            smem.k.red[grp][o] = mx;
            __syncthreads();

            if (t < DOUT) {
                float v = fmaxf(fmaxf(smem.k.red[0][t], smem.k.red[1][t]),
                                fmaxf(smem.k.red[2][t], smem.k.red[3][t]));
                outF[(size_t)q * DOUT + t] = v;
            }
            __syncthreads();
        }
    }
}

extern "C" void kernel_launch(void* const* d_in, const int* in_sizes, int n_in,
                              void* d_out, int out_size, void* d_ws, size_t ws_size,
                              hipStream_t stream)
{
    const float* coords = (const float*)d_in[0];
    const float* feat   = (const float*)d_in[1];
    const float* W      = (const float*)d_in[2];
    const float* bias   = (const float*)d_in[3];
    const float* gamma  = (const float*)d_in[4];
    const float* beta   = (const float*)d_in[5];
    const float* rmean  = (const float*)d_in[6];
    const float* rvar   = (const float*)d_in[7];

    float* out_coords = (float*)d_out;                    // [8,2048,3]
    float* out_feat   = out_coords + (size_t)NB * NS * 3; // [8,2048,128]

    char* ws = (char*)d_ws;
    float*    Wt    = (float*)ws;                         // 32 KB
    float*    Cb    = (float*)(ws + 32768);               // 512 B
    unsigned* flags = (unsigned*)(ws + 40960);            // 8 flags, 64B apart

    hipMemsetAsync(flags, 0, 8 * 16 * sizeof(unsigned), stream);
    fold_weights_kernel<<<(DIN * DOUT + 255) / 256, 256, 0, stream>>>(
        W, bias, gamma, beta, rmean, rvar, Wt, Cb);
    mega_kernel<<<NB + NW, MT, 0, stream>>>(
        coords, out_coords, feat, Wt, Cb, out_feat, flags);
}